// Round 12
// baseline (146.232 us; speedup 1.0000x reference)
//
#include <hip/hip_runtime.h>
#include <hip/hip_bf16.h>

// GraphLSTM fused kernel for MI355X — R11: single-kernel, zero-atomic.
// R9's block-per-node structure (dst_idx sorted in [MN,E) -> node n's edges =
// {n} u contiguous [lo,hi)) was right; its 159us was pure register spill
// (VGPR_Count=64, ~229MB scratch writes). Fix with waves_per_eu(4,4).
// New vs R9: (1) in-kernel binary search for lo/hi (waves 0-1 search lo,
// waves 2-3 search hi, exchange via LDS) -> prep kernel deleted; (2) x
// gathered directly from (B,D,MN) layout, one dword/lane, L2-resident
// (x = 256KB) -> xt transpose deleted. One launch, no atomics, no scratch.

#define MN 1024
#define BB 8

__device__ __forceinline__ float fsig(float x) {
    return __builtin_amdgcn_rcpf(1.0f + __expf(-x));
}
__device__ __forceinline__ float ftanh(float x) {
    float t = fminf(fmaxf(2.0f * x, -30.0f), 30.0f);   // avoid inf/inf
    float e = __expf(t);
    return (e - 1.0f) * __builtin_amdgcn_rcpf(e + 1.0f);
}
__device__ __forceinline__ float rl(float v, int idx) {
    return __int_as_float(__builtin_amdgcn_readlane(__float_as_int(v), idx));
}

struct WRegs {
    float4 wi0, wi1, wg0, wg1, wo0, wo1;   // 24 VGPR
    float  bIi, bIh, bGi, bGh, bOi, bOh;   // 6 VGPR
};

__device__ __forceinline__ void loadW(WRegs& r, int e, int lane,
        const float* __restrict__ W, const float* __restrict__ b_ih,
        const float* __restrict__ b_hh) {
    const float* We = W + (size_t)e * 2048 + lane * 8;
    r.wi0 = *(const float4*)(We);
    r.wi1 = *(const float4*)(We + 4);
    r.wg0 = *(const float4*)(We + 1024);
    r.wg1 = *(const float4*)(We + 1028);
    r.wo0 = *(const float4*)(We + 1536);
    r.wo1 = *(const float4*)(We + 1540);
    const float* bi = b_ih + (size_t)e * 256 + lane;
    const float* bh = b_hh + (size_t)e * 256 + lane;
    r.bIi = bi[0];   r.bIh = bh[0];
    r.bGi = bi[128]; r.bGh = bh[128];
    r.bOi = bi[192]; r.bOh = bh[192];
}

// Compute one edge; accumulate cwew*h into vacc[b] (no fold, no atomic).
__device__ __forceinline__ void computeEdge(const WRegs& r, float xreg,
        float cwew, float* vacc) {
    float bI = r.bIi + r.bIh;
    float bG = r.bGi + r.bGh;
    float bO = r.bOi + r.bOh;
#pragma unroll
    for (int b = 0; b < BB; ++b) {
        float x0 = rl(xreg, b * 8 + 0), x1 = rl(xreg, b * 8 + 1);
        float x2 = rl(xreg, b * 8 + 2), x3 = rl(xreg, b * 8 + 3);
        float x4 = rl(xreg, b * 8 + 4), x5 = rl(xreg, b * 8 + 5);
        float x6 = rl(xreg, b * 8 + 6), x7 = rl(xreg, b * 8 + 7);
        float pi = bI, pg = bG, po = bO;
        pi = fmaf(r.wi0.x, x0, pi); pg = fmaf(r.wg0.x, x0, pg); po = fmaf(r.wo0.x, x0, po);
        pi = fmaf(r.wi0.y, x1, pi); pg = fmaf(r.wg0.y, x1, pg); po = fmaf(r.wo0.y, x1, po);
        pi = fmaf(r.wi0.z, x2, pi); pg = fmaf(r.wg0.z, x2, pg); po = fmaf(r.wo0.z, x2, po);
        pi = fmaf(r.wi0.w, x3, pi); pg = fmaf(r.wg0.w, x3, pg); po = fmaf(r.wo0.w, x3, po);
        pi = fmaf(r.wi1.x, x4, pi); pg = fmaf(r.wg1.x, x4, pg); po = fmaf(r.wo1.x, x4, po);
        pi = fmaf(r.wi1.y, x5, pi); pg = fmaf(r.wg1.y, x5, pg); po = fmaf(r.wo1.y, x5, po);
        pi = fmaf(r.wi1.z, x6, pi); pg = fmaf(r.wg1.z, x6, pg); po = fmaf(r.wo1.z, x6, po);
        pi = fmaf(r.wi1.w, x7, pi); pg = fmaf(r.wg1.w, x7, pg); po = fmaf(r.wo1.w, x7, po);
        float c = fsig(pi) * ftanh(pg);
        float h = fsig(po) * ftanh(c);
        vacc[b] = fmaf(cwew, h, vacc[b]);
    }
}

__global__ __launch_bounds__(256)
__attribute__((amdgpu_waves_per_eu(4, 4)))   // 128 VGPR budget -> no spill
void fused_kernel(
        const float* __restrict__ x,       // (B, D, MN) original layout
        const float* __restrict__ edge_w,  // (E)
        const float* __restrict__ W,       // (E, 256, 8)
        const float* __restrict__ b_ih,    // (E, 256)
        const float* __restrict__ b_hh,    // (E, 256)
        const float* __restrict__ conv_w,  // (1, 64)
        const int*   __restrict__ src_idx,
        const int*   __restrict__ dst_idx, // sorted in [MN, E)
        const float* __restrict__ conv_b,  // (1)
        float* __restrict__ out,           // (B, MN) written directly
        int E) {
    int lane = threadIdx.x & 63;
    int w    = threadIdx.x >> 6;
    int n    = blockIdx.x;                 // block <-> node

    __shared__ int   bounds[2];
    __shared__ float lds[4][BB][64];

    // In-kernel CSR bounds: waves 0-1 search lower_bound(n), 2-3 search
    // lower_bound(n+1) over the sorted dst range [MN, E). Uniform scalar
    // search (~15 L2-warm probes), exchanged via LDS.
    {
        int target = (w < 2) ? n : n + 1;
        int l = MN, r = E;
        while (l < r) {
            int m = (l + r) >> 1;
            if (dst_idx[m] < target) l = m + 1; else r = m;
        }
        if (lane == 0) bounds[w >> 1] = l;   // benign same-value race
    }
    __syncthreads();
    int lo  = bounds[0], hi = bounds[1];
    int len = 1 + (hi - lo);               // j=0 self edge, j>=1 -> lo+j-1
    int jC   = (w * len) >> 2;             // this wave's contiguous quarter
    int jEnd = ((w + 1) * len) >> 2;
    float cw = conv_w[lane];
    int xoff = (lane >> 3) * (8 * MN) + (lane & 7) * MN;  // (b,d) gather base

    float vacc[BB];
#pragma unroll
    for (int b = 0; b < BB; ++b) vacc[b] = 0.0f;

    if (jC < jEnd) {
        int jN = jC + 1, jN2 = jC + 2;
        int eC = (jC == 0) ? n : lo + jC - 1;
        int   srcC = src_idx[eC];
        float ewC  = edge_w[eC];
        int srcN = 0; float ewN = 0.0f;
        if (jN < jEnd) {                   // jN >= 1 always
            int eN = lo + jN - 1;
            srcN = src_idx[eN]; ewN = edge_w[eN];
        }

        WRegs A, B;
        loadW(A, eC, lane, W, b_ih, b_hh);
        float xA = x[xoff + srcC];         // 1 dword/lane gather, L2-resident
        float xB = 0.0f;
        bool useA = true;

        while (true) {
            bool hasN  = (jN  < jEnd);
            bool hasN2 = (jN2 < jEnd);
            int srcN2 = 0; float ewN2 = 0.0f;
            if (hasN2) {
                int eN2 = lo + jN2 - 1;
                srcN2 = src_idx[eN2]; ewN2 = edge_w[eN2];
            }

            // Prefetch W + x for edge jN (srcN s_loaded last iteration).
            if (hasN) {
                int eN = lo + jN - 1;
                if (useA) { loadW(B, eN, lane, W, b_ih, b_hh);
                            xB = x[xoff + srcN]; }
                else      { loadW(A, eN, lane, W, b_ih, b_hh);
                            xA = x[xoff + srcN]; }
            }
            __builtin_amdgcn_sched_barrier(0);

            float cwew = ewC * cw;
            if (useA) computeEdge(A, xA, cwew, vacc);
            else      computeEdge(B, xB, cwew, vacc);

            if (!hasN) break;
            srcC = srcN; ewC = ewN;
            srcN = srcN2; ewN = ewN2;
            jC = jN; jN = jN2; ++jN2;
            useA = !useA;
        }
    }

    // Block combine: 4 waves -> LDS -> wave 0 folds once and stores.
#pragma unroll
    for (int b = 0; b < BB; ++b) lds[w][b][lane] = vacc[b];
    __syncthreads();
    if (w == 0) {
        float val[BB];
#pragma unroll
        for (int b = 0; b < BB; ++b)
            val[b] = (lds[0][b][lane] + lds[1][b][lane]) +
                     (lds[2][b][lane] + lds[3][b][lane]);
        // Batch-folding reduction over 64 lanes (sum over h), 10 shuffles.
        float u[4];
#pragma unroll
        for (int k = 0; k < 4; ++k) {
            float keep = (lane & 32) ? val[k + 4] : val[k];
            float send = (lane & 32) ? val[k]     : val[k + 4];
            u[k] = keep + __shfl_xor(send, 32, 64);
        }
        float v[2];
#pragma unroll
        for (int k = 0; k < 2; ++k) {
            float keep = (lane & 16) ? u[k + 2] : u[k];
            float send = (lane & 16) ? u[k]     : u[k + 2];
            v[k] = keep + __shfl_xor(send, 16, 64);
        }
        float keep = (lane & 8) ? v[1] : v[0];
        float send = (lane & 8) ? v[0] : v[1];
        float t = keep + __shfl_xor(send, 8, 64);
        t += __shfl_xor(t, 4, 64);
        t += __shfl_xor(t, 2, 64);
        t += __shfl_xor(t, 1, 64);
        if ((lane & 7) == 0) {
            int b = lane >> 3;
            out[b * MN + n] = t + conv_b[0];
        }
    }
}

extern "C" void kernel_launch(void* const* d_in, const int* in_sizes, int n_in,
                              void* d_out, int out_size, void* d_ws, size_t ws_size,
                              hipStream_t stream) {
    const float* x      = (const float*)d_in[0];
    const float* edge_w = (const float*)d_in[1];
    const float* W_ih   = (const float*)d_in[2];
    const float* b_ih   = (const float*)d_in[3];
    const float* b_hh   = (const float*)d_in[4];
    const float* conv_w = (const float*)d_in[5];
    const float* conv_b = (const float*)d_in[6];
    const int* src_idx  = (const int*)d_in[7];
    const int* dst_idx  = (const int*)d_in[8];
    int E = in_sizes[1];

    // Single launch: one block per node; 1024 blocks = 4/CU, co-resident.
    fused_kernel<<<MN, 256, 0, stream>>>(x, edge_w, W_ih, b_ih, b_hh,
                                         conv_w, src_idx, dst_idx, conv_b,
                                         (float*)d_out, E);
}

// Round 13
// 118.047 us; speedup vs baseline: 1.2388x; 1.2388x over previous
//
#include <hip/hip_runtime.h>
#include <hip/hip_bf16.h>

// GraphLSTM fused kernel for MI355X — R13: dst-run accumulation, no partials.
// dst_idx in [MN,E) is sorted (np.nonzero row-major) with ~33-long equal-dst
// runs. Chunked contiguous per-wave edge ranges (~8.5 edges) -> a chunk spans
// 1-2 runs: accumulate vacc[b] per run, fold+atomic only on dst change or
// chunk end (~4x fewer atomics, ~9 per output address -> no privatization
// needed). Deletes the 1MB partial zeroing and the reduce kernel entirely.
// Read path + ping-pong pipeline + launch_bounds identical to R8 (proven
// no-spill at 63.65us).

#define MN 1024
#define BB 8

__device__ __forceinline__ float fsig(float x) {
    return __builtin_amdgcn_rcpf(1.0f + __expf(-x));
}
__device__ __forceinline__ float ftanh(float x) {
    float t = fminf(fmaxf(2.0f * x, -30.0f), 30.0f);   // avoid inf/inf
    float e = __expf(t);
    return (e - 1.0f) * __builtin_amdgcn_rcpf(e + 1.0f);
}
__device__ __forceinline__ float rl(float v, int idx) {
    return __int_as_float(__builtin_amdgcn_readlane(__float_as_int(v), idx));
}

// Prep: transpose x (B,D,MN) -> xt (MN,B,D); init out = conv_b (re-init every
// call: atomics accumulate into out during edge_kernel).
__global__ void prep_kernel(const float* __restrict__ x,
                            const float* __restrict__ conv_b,
                            float* __restrict__ xt,
                            float* __restrict__ out) {
    int tid = blockIdx.x * 256 + threadIdx.x;   // 65536 threads
    if (tid < MN * BB * 8) {
        int mn = tid >> 6;
        int b  = (tid >> 3) & 7;
        int d  = tid & 7;
        xt[tid] = x[b * (8 * MN) + d * MN + mn];
    }
    if (tid < BB * MN) out[tid] = conv_b[0];
}

struct WRegs {
    float4 wi0, wi1, wg0, wg1, wo0, wo1;   // 24 VGPR
    float  bIi, bIh, bGi, bGh, bOi, bOh;   // 6 VGPR
};

__device__ __forceinline__ void loadW(WRegs& r, int e, int lane,
        const float* __restrict__ W, const float* __restrict__ b_ih,
        const float* __restrict__ b_hh) {
    const float* We = W + (size_t)e * 2048 + lane * 8;
    r.wi0 = *(const float4*)(We);
    r.wi1 = *(const float4*)(We + 4);
    r.wg0 = *(const float4*)(We + 1024);
    r.wg1 = *(const float4*)(We + 1028);
    r.wo0 = *(const float4*)(We + 1536);
    r.wo1 = *(const float4*)(We + 1540);
    const float* bi = b_ih + (size_t)e * 256 + lane;
    const float* bh = b_hh + (size_t)e * 256 + lane;
    r.bIi = bi[0];   r.bIh = bh[0];
    r.bGi = bi[128]; r.bGh = bh[128];
    r.bOi = bi[192]; r.bOh = bh[192];
}

// Compute one edge; accumulate cwew*h into vacc[b].
__device__ __forceinline__ void computeEdge(const WRegs& r, float xreg,
        float cwew, float* vacc) {
    float bI = r.bIi + r.bIh;
    float bG = r.bGi + r.bGh;
    float bO = r.bOi + r.bOh;
#pragma unroll
    for (int b = 0; b < BB; ++b) {
        float x0 = rl(xreg, b * 8 + 0), x1 = rl(xreg, b * 8 + 1);
        float x2 = rl(xreg, b * 8 + 2), x3 = rl(xreg, b * 8 + 3);
        float x4 = rl(xreg, b * 8 + 4), x5 = rl(xreg, b * 8 + 5);
        float x6 = rl(xreg, b * 8 + 6), x7 = rl(xreg, b * 8 + 7);
        float pi = bI, pg = bG, po = bO;
        pi = fmaf(r.wi0.x, x0, pi); pg = fmaf(r.wg0.x, x0, pg); po = fmaf(r.wo0.x, x0, po);
        pi = fmaf(r.wi0.y, x1, pi); pg = fmaf(r.wg0.y, x1, pg); po = fmaf(r.wo0.y, x1, po);
        pi = fmaf(r.wi0.z, x2, pi); pg = fmaf(r.wg0.z, x2, pg); po = fmaf(r.wo0.z, x2, po);
        pi = fmaf(r.wi0.w, x3, pi); pg = fmaf(r.wg0.w, x3, pg); po = fmaf(r.wo0.w, x3, po);
        pi = fmaf(r.wi1.x, x4, pi); pg = fmaf(r.wg1.x, x4, pg); po = fmaf(r.wo1.x, x4, po);
        pi = fmaf(r.wi1.y, x5, pi); pg = fmaf(r.wg1.y, x5, pg); po = fmaf(r.wo1.y, x5, po);
        pi = fmaf(r.wi1.z, x6, pi); pg = fmaf(r.wg1.z, x6, pg); po = fmaf(r.wo1.z, x6, po);
        pi = fmaf(r.wi1.w, x7, pi); pg = fmaf(r.wg1.w, x7, pg); po = fmaf(r.wo1.w, x7, po);
        float c = fsig(pi) * ftanh(pg);
        float h = fsig(po) * ftanh(c);
        vacc[b] = fmaf(cwew, h, vacc[b]);
    }
}

// Fold vacc over 64 lanes (batch-folding butterfly, 10 shuffles) and emit
// one 8-lane-active atomic instruction to out[b*MN + dst].
__device__ __forceinline__ void foldAtomic(float* vacc, int dst,
        float* __restrict__ out, int lane) {
    float u[4];
#pragma unroll
    for (int k = 0; k < 4; ++k) {
        float keep = (lane & 32) ? vacc[k + 4] : vacc[k];
        float send = (lane & 32) ? vacc[k]     : vacc[k + 4];
        u[k] = keep + __shfl_xor(send, 32, 64);
    }
    float v[2];
#pragma unroll
    for (int k = 0; k < 2; ++k) {
        float keep = (lane & 16) ? u[k + 2] : u[k];
        float send = (lane & 16) ? u[k]     : u[k + 2];
        v[k] = keep + __shfl_xor(send, 16, 64);
    }
    float keep = (lane & 8) ? v[1] : v[0];
    float send = (lane & 8) ? v[0] : v[1];
    float t = keep + __shfl_xor(send, 8, 64);
    t += __shfl_xor(t, 4, 64);
    t += __shfl_xor(t, 2, 64);
    t += __shfl_xor(t, 1, 64);
    if ((lane & 7) == 0) {
        int b = lane >> 3;
        atomicAdd(out + b * MN + dst, t);
    }
}

__global__ __launch_bounds__(256, 4) void edge_kernel(
        const float* __restrict__ xt,      // (MN, B, D)
        const float* __restrict__ edge_w,  // (E)
        const float* __restrict__ W,       // (E, 256, 8)
        const float* __restrict__ b_ih,    // (E, 256)
        const float* __restrict__ b_hh,    // (E, 256)
        const float* __restrict__ conv_w,  // (1, 64)
        const int*   __restrict__ src_idx,
        const int*   __restrict__ dst_idx,
        float* __restrict__ out,           // (B, MN), pre-init to conv_b
        int E) {
    int lane = threadIdx.x & 63;
    int nW = gridDim.x * 4;
    int wid = __builtin_amdgcn_readfirstlane(blockIdx.x * 4 + (threadIdx.x >> 6));
    // Contiguous chunk (dst runs are contiguous -> few folds per chunk).
    int eC   = (int)((long long)wid * E / nW);
    int eEnd = (int)((long long)(wid + 1) * E / nW);
    if (eC >= eEnd) return;
    float cw = conv_w[lane];

    float vacc[BB];
#pragma unroll
    for (int b = 0; b < BB; ++b) vacc[b] = 0.0f;

    int eN = eC + 1, eN2 = eC + 2;
    int   srcC = src_idx[eC], dstC = dst_idx[eC];
    float ewC  = edge_w[eC];
    int srcN = 0, dstN = 0; float ewN = 0.0f;
    if (eN < eEnd) { srcN = src_idx[eN]; dstN = dst_idx[eN]; ewN = edge_w[eN]; }

    WRegs A, B;
    loadW(A, eC, lane, W, b_ih, b_hh);
    float xA = xt[(size_t)srcC * 64 + lane];
    float xB = 0.0f;
    bool useA = true;

    while (true) {
        bool hasN  = (eN  < eEnd);
        bool hasN2 = (eN2 < eEnd);
        int srcN2 = 0, dstN2 = 0; float ewN2 = 0.0f;
        if (hasN2) { srcN2 = src_idx[eN2]; dstN2 = dst_idx[eN2]; ewN2 = edge_w[eN2]; }

        // Prefetch W + x for edge N (srcN s_loaded last iteration — no wait).
        if (hasN) {
            if (useA) { loadW(B, eN, lane, W, b_ih, b_hh);
                        xB = xt[(size_t)srcN * 64 + lane]; }
            else      { loadW(A, eN, lane, W, b_ih, b_hh);
                        xA = xt[(size_t)srcN * 64 + lane]; }
        }
        __builtin_amdgcn_sched_barrier(0);

        // Compute edge C into vacc — operands arrived during previous compute.
        float cwew = ewC * cw;
        if (useA) computeEdge(A, xA, cwew, vacc);
        else      computeEdge(B, xB, cwew, vacc);

        // Flush on dst change or chunk end (wave-uniform branch; runs ~33
        // long, chunk ~8.5 edges -> ~1-2 flushes per chunk).
        if (!hasN || dstN != dstC) {
            foldAtomic(vacc, dstC, out, lane);
#pragma unroll
            for (int b = 0; b < BB; ++b) vacc[b] = 0.0f;
        }

        if (!hasN) break;
        srcC = srcN; dstC = dstN; ewC = ewN;
        srcN = srcN2; dstN = dstN2; ewN = ewN2;
        eC = eN; eN = eN2; ++eN2;
        useA = !useA;
    }
}

extern "C" void kernel_launch(void* const* d_in, const int* in_sizes, int n_in,
                              void* d_out, int out_size, void* d_ws, size_t ws_size,
                              hipStream_t stream) {
    const float* x      = (const float*)d_in[0];
    const float* edge_w = (const float*)d_in[1];
    const float* W_ih   = (const float*)d_in[2];
    const float* b_ih   = (const float*)d_in[3];
    const float* b_hh   = (const float*)d_in[4];
    const float* conv_w = (const float*)d_in[5];
    const float* conv_b = (const float*)d_in[6];
    const int* src_idx  = (const int*)d_in[7];
    const int* dst_idx  = (const int*)d_in[8];
    int E = in_sizes[1];

    float* xt  = (float*)d_ws;      // 65536 floats = 256 KB
    float* out = (float*)d_out;     // 8192 floats

    prep_kernel<<<256, 256, 0, stream>>>(x, conv_b, xt, out);

    // Persistent grid: 4 blocks/CU x 256 CUs = 16 waves/CU.
    edge_kernel<<<1024, 256, 0, stream>>>(xt, edge_w, W_ih, b_ih, b_hh,
                                          conv_w, src_idx, dst_idx, out, E);
}

// Round 14
// 57.655 us; speedup vs baseline: 2.5363x; 2.0475x over previous
//
#include <hip/hip_runtime.h>
#include <hip/hip_bf16.h>

// GraphLSTM fused kernel for MI355X — R14: spill-proof TLP design.
// Allocator pathology (R9/R11/R13): any loop-persistent vacc[] -> VGPR=64 +
// massive scratch, immune to waves_per_eu attributes. Fix by construction:
// single WRegs buffer, live set ~60 VGPR -> cannot spill under any budget.
// Latency hiding moves from in-wave ping-pong (R8) to TLP: launch_bounds
// (256,6) + grid 1536 = 24 waves/CU (vs R8's ~16), +50% outstanding-load
// depth. Proven pieces kept: idx prefetch 1 ahead, per-edge fold, x32
// privatized atomics, prep transpose + reduce.

#define MN 1024
#define BB 8
#define NCOPY 32

__device__ __forceinline__ float fsig(float x) {
    return __builtin_amdgcn_rcpf(1.0f + __expf(-x));
}
__device__ __forceinline__ float ftanh(float x) {
    float t = fminf(fmaxf(2.0f * x, -30.0f), 30.0f);   // avoid inf/inf
    float e = __expf(t);
    return (e - 1.0f) * __builtin_amdgcn_rcpf(e + 1.0f);
}
__device__ __forceinline__ float rl(float v, int idx) {
    return __int_as_float(__builtin_amdgcn_readlane(__float_as_int(v), idx));
}

// Prep: transpose x (B,D,MN) -> xt (MN,B,D); zero the 32 partial buffers.
__global__ void prep_kernel(const float* __restrict__ x,
                            float* __restrict__ xt,
                            float* __restrict__ partial) {
    int tid = blockIdx.x * 256 + threadIdx.x;   // 65536 threads
    if (tid < MN * BB * 8) {
        int mn = tid >> 6;
        int b  = (tid >> 3) & 7;
        int d  = tid & 7;
        xt[tid] = x[b * (8 * MN) + d * MN + mn];
    }
    // Zero 32 x 8192 floats (4 per thread), every launch (replay-safe).
    float4* p4 = (float4*)partial;
    p4[tid] = make_float4(0.f, 0.f, 0.f, 0.f);
}

// Reduce: out[t] = conv_b + sum_k partial[k][t].
__global__ void reduce_kernel(const float* __restrict__ partial,
                              const float* __restrict__ conv_b,
                              float* __restrict__ out) {
    int tid = blockIdx.x * 256 + threadIdx.x;   // 8192 threads
    float s = conv_b[0];
#pragma unroll
    for (int k = 0; k < NCOPY; ++k) s += partial[k * (BB * MN) + tid];
    out[tid] = s;
}

struct WRegs {
    float4 wi0, wi1, wg0, wg1, wo0, wo1;   // 24 VGPR
    float  bIi, bIh, bGi, bGh, bOi, bOh;   // 6 VGPR
};

__device__ __forceinline__ void loadW(WRegs& r, int e, int lane,
        const float* __restrict__ W, const float* __restrict__ b_ih,
        const float* __restrict__ b_hh) {
    const float* We = W + (size_t)e * 2048 + lane * 8;
    r.wi0 = *(const float4*)(We);
    r.wi1 = *(const float4*)(We + 4);
    r.wg0 = *(const float4*)(We + 1024);
    r.wg1 = *(const float4*)(We + 1028);
    r.wo0 = *(const float4*)(We + 1536);
    r.wo1 = *(const float4*)(We + 1540);
    const float* bi = b_ih + (size_t)e * 256 + lane;
    const float* bh = b_hh + (size_t)e * 256 + lane;
    r.bIi = bi[0];   r.bIh = bh[0];
    r.bGi = bi[128]; r.bGh = bh[128];
    r.bOi = bi[192]; r.bOh = bh[192];
}

__device__ __forceinline__ void computeEdge(const WRegs& r, float xreg,
        int dst, float ew, float cw, float* __restrict__ pout, int lane) {
    float bI = r.bIi + r.bIh;
    float bG = r.bGi + r.bGh;
    float bO = r.bOi + r.bOh;
    float s[BB];
#pragma unroll
    for (int b = 0; b < BB; ++b) {
        float x0 = rl(xreg, b * 8 + 0), x1 = rl(xreg, b * 8 + 1);
        float x2 = rl(xreg, b * 8 + 2), x3 = rl(xreg, b * 8 + 3);
        float x4 = rl(xreg, b * 8 + 4), x5 = rl(xreg, b * 8 + 5);
        float x6 = rl(xreg, b * 8 + 6), x7 = rl(xreg, b * 8 + 7);
        float pi = bI, pg = bG, po = bO;
        pi = fmaf(r.wi0.x, x0, pi); pg = fmaf(r.wg0.x, x0, pg); po = fmaf(r.wo0.x, x0, po);
        pi = fmaf(r.wi0.y, x1, pi); pg = fmaf(r.wg0.y, x1, pg); po = fmaf(r.wo0.y, x1, po);
        pi = fmaf(r.wi0.z, x2, pi); pg = fmaf(r.wg0.z, x2, pg); po = fmaf(r.wo0.z, x2, po);
        pi = fmaf(r.wi0.w, x3, pi); pg = fmaf(r.wg0.w, x3, pg); po = fmaf(r.wo0.w, x3, po);
        pi = fmaf(r.wi1.x, x4, pi); pg = fmaf(r.wg1.x, x4, pg); po = fmaf(r.wo1.x, x4, po);
        pi = fmaf(r.wi1.y, x5, pi); pg = fmaf(r.wg1.y, x5, pg); po = fmaf(r.wo1.y, x5, po);
        pi = fmaf(r.wi1.z, x6, pi); pg = fmaf(r.wg1.z, x6, pg); po = fmaf(r.wo1.z, x6, po);
        pi = fmaf(r.wi1.w, x7, pi); pg = fmaf(r.wg1.w, x7, pg); po = fmaf(r.wo1.w, x7, po);
        float c = fsig(pi) * ftanh(pg);
        float h = fsig(po) * ftanh(c);
        s[b] = cw * h;
    }
    // Batch-folding reduction over 64 lanes (Σ_h), 10 shuffles total.
    float u[4];
#pragma unroll
    for (int k = 0; k < 4; ++k) {
        float keep = (lane & 32) ? s[k + 4] : s[k];
        float send = (lane & 32) ? s[k]     : s[k + 4];
        u[k] = keep + __shfl_xor(send, 32, 64);
    }
    float v[2];
#pragma unroll
    for (int k = 0; k < 2; ++k) {
        float keep = (lane & 16) ? u[k + 2] : u[k];
        float send = (lane & 16) ? u[k]     : u[k + 2];
        v[k] = keep + __shfl_xor(send, 16, 64);
    }
    float keep = (lane & 8) ? v[1] : v[0];
    float send = (lane & 8) ? v[0] : v[1];
    float t = keep + __shfl_xor(send, 8, 64);
    t += __shfl_xor(t, 4, 64);
    t += __shfl_xor(t, 2, 64);
    t += __shfl_xor(t, 1, 64);
    if ((lane & 7) == 0) {
        int b = lane >> 3;
        atomicAdd(pout + b * MN + dst, ew * t);
    }
}

__global__ __launch_bounds__(256, 6) void edge_kernel(
        const float* __restrict__ xt,      // (MN, B, D)
        const float* __restrict__ edge_w,  // (E)
        const float* __restrict__ W,       // (E, 256, 8)
        const float* __restrict__ b_ih,    // (E, 256)
        const float* __restrict__ b_hh,    // (E, 256)
        const float* __restrict__ conv_w,  // (1, 64)
        const int*   __restrict__ src_idx,
        const int*   __restrict__ dst_idx,
        float* __restrict__ partial,       // (NCOPY, B, MN) zeroed by prep
        int E) {
    int lane = threadIdx.x & 63;
    int nw = gridDim.x * 4;
    int wid = blockIdx.x * 4 + (threadIdx.x >> 6);
    int e = __builtin_amdgcn_readfirstlane(wid);
    if (e >= E) return;
    float cw = conv_w[lane];
    float* pout = partial + (size_t)(wid & (NCOPY - 1)) * (BB * MN);

    // Prologue idx for first edge.
    int   srcC = src_idx[e], dstC = dst_idx[e];
    float ewC  = edge_w[e];

    while (true) {
        int eN = e + nw;
        bool hasN = (eN < E);
        // idx for next edge (s_load; hidden under this edge's load+compute).
        int srcN = 0, dstN = 0; float ewN = 0.0f;
        if (hasN) { srcN = src_idx[eN]; dstN = dst_idx[eN]; ewN = edge_w[eN]; }

        // Current edge: W burst + x gather, then compute (TLP hides the wait:
        // 6 waves/SIMD each with an independent burst in flight).
        WRegs A;
        loadW(A, e, lane, W, b_ih, b_hh);
        float xA = xt[(size_t)srcC * 64 + lane];
        computeEdge(A, xA, dstC, ewC, cw, pout, lane);

        if (!hasN) break;
        e = eN; srcC = srcN; dstC = dstN; ewC = ewN;
    }
}

extern "C" void kernel_launch(void* const* d_in, const int* in_sizes, int n_in,
                              void* d_out, int out_size, void* d_ws, size_t ws_size,
                              hipStream_t stream) {
    const float* x      = (const float*)d_in[0];
    const float* edge_w = (const float*)d_in[1];
    const float* W_ih   = (const float*)d_in[2];
    const float* b_ih   = (const float*)d_in[3];
    const float* b_hh   = (const float*)d_in[4];
    const float* conv_w = (const float*)d_in[5];
    const float* conv_b = (const float*)d_in[6];
    const int* src_idx  = (const int*)d_in[7];
    const int* dst_idx  = (const int*)d_in[8];
    int E = in_sizes[1];

    float* xt      = (float*)d_ws;             // 65536 floats = 256 KB
    float* partial = (float*)d_ws + 65536;     // 32 x 8192 floats = 1 MB
    float* out     = (float*)d_out;            // 8192 floats

    prep_kernel<<<256, 256, 0, stream>>>(x, xt, partial);

    // 1536 blocks = 6/CU resident (launch_bounds(256,6)) = 24 waves/CU.
    edge_kernel<<<1536, 256, 0, stream>>>(xt, edge_w, W_ih, b_ih, b_hh,
                                          conv_w, src_idx, dst_idx, partial, E);

    reduce_kernel<<<32, 256, 0, stream>>>(partial, conv_b, out);
}

// Round 15
// 56.923 us; speedup vs baseline: 2.5689x; 1.0128x over previous
//
#include <hip/hip_runtime.h>
#include <hip/hip_bf16.h>

// GraphLSTM fused kernel for MI355X — R15: R14 + max TLP (8 waves/SIMD).
// R14 proved the lever: TLP (not in-wave pipelining) hides this kernel's
// HBM latency (63.65 -> 57.65 at 6 waves/SIMD). R15 pushes to the HW max:
// launch_bounds(256,8) (64-VGPR budget) + grid 2048 = 32 waves/CU.
// Bias pairs combined at load (6 regs -> 3) to keep live set ~50-55 VGPR,
// comfortably under 64. Otherwise identical to R14.

#define MN 1024
#define BB 8
#define NCOPY 32

__device__ __forceinline__ float fsig(float x) {
    return __builtin_amdgcn_rcpf(1.0f + __expf(-x));
}
__device__ __forceinline__ float ftanh(float x) {
    float t = fminf(fmaxf(2.0f * x, -30.0f), 30.0f);   // avoid inf/inf
    float e = __expf(t);
    return (e - 1.0f) * __builtin_amdgcn_rcpf(e + 1.0f);
}
__device__ __forceinline__ float rl(float v, int idx) {
    return __int_as_float(__builtin_amdgcn_readlane(__float_as_int(v), idx));
}

// Prep: transpose x (B,D,MN) -> xt (MN,B,D); zero the 32 partial buffers.
__global__ void prep_kernel(const float* __restrict__ x,
                            float* __restrict__ xt,
                            float* __restrict__ partial) {
    int tid = blockIdx.x * 256 + threadIdx.x;   // 65536 threads
    if (tid < MN * BB * 8) {
        int mn = tid >> 6;
        int b  = (tid >> 3) & 7;
        int d  = tid & 7;
        xt[tid] = x[b * (8 * MN) + d * MN + mn];
    }
    // Zero 32 x 8192 floats (4 per thread), every launch (replay-safe).
    float4* p4 = (float4*)partial;
    p4[tid] = make_float4(0.f, 0.f, 0.f, 0.f);
}

// Reduce: out[t] = conv_b + sum_k partial[k][t].
__global__ void reduce_kernel(const float* __restrict__ partial,
                              const float* __restrict__ conv_b,
                              float* __restrict__ out) {
    int tid = blockIdx.x * 256 + threadIdx.x;   // 8192 threads
    float s = conv_b[0];
#pragma unroll
    for (int k = 0; k < NCOPY; ++k) s += partial[k * (BB * MN) + tid];
    out[tid] = s;
}

struct WRegs {
    float4 wi0, wi1, wg0, wg1, wo0, wo1;   // 24 VGPR
    float  bI, bG, bO;                     // 3 VGPR (pairs combined at load)
};

__device__ __forceinline__ void loadW(WRegs& r, int e, int lane,
        const float* __restrict__ W, const float* __restrict__ b_ih,
        const float* __restrict__ b_hh) {
    const float* We = W + (size_t)e * 2048 + lane * 8;
    r.wi0 = *(const float4*)(We);
    r.wi1 = *(const float4*)(We + 4);
    r.wg0 = *(const float4*)(We + 1024);
    r.wg1 = *(const float4*)(We + 1028);
    r.wo0 = *(const float4*)(We + 1536);
    r.wo1 = *(const float4*)(We + 1540);
    const float* bi = b_ih + (size_t)e * 256 + lane;
    const float* bh = b_hh + (size_t)e * 256 + lane;
    r.bI = bi[0]   + bh[0];
    r.bG = bi[128] + bh[128];
    r.bO = bi[192] + bh[192];
}

__device__ __forceinline__ void computeEdge(const WRegs& r, float xreg,
        int dst, float ew, float cw, float* __restrict__ pout, int lane) {
    float s[BB];
#pragma unroll
    for (int b = 0; b < BB; ++b) {
        float x0 = rl(xreg, b * 8 + 0), x1 = rl(xreg, b * 8 + 1);
        float x2 = rl(xreg, b * 8 + 2), x3 = rl(xreg, b * 8 + 3);
        float x4 = rl(xreg, b * 8 + 4), x5 = rl(xreg, b * 8 + 5);
        float x6 = rl(xreg, b * 8 + 6), x7 = rl(xreg, b * 8 + 7);
        float pi = r.bI, pg = r.bG, po = r.bO;
        pi = fmaf(r.wi0.x, x0, pi); pg = fmaf(r.wg0.x, x0, pg); po = fmaf(r.wo0.x, x0, po);
        pi = fmaf(r.wi0.y, x1, pi); pg = fmaf(r.wg0.y, x1, pg); po = fmaf(r.wo0.y, x1, po);
        pi = fmaf(r.wi0.z, x2, pi); pg = fmaf(r.wg0.z, x2, pg); po = fmaf(r.wo0.z, x2, po);
        pi = fmaf(r.wi0.w, x3, pi); pg = fmaf(r.wg0.w, x3, pg); po = fmaf(r.wo0.w, x3, po);
        pi = fmaf(r.wi1.x, x4, pi); pg = fmaf(r.wg1.x, x4, pg); po = fmaf(r.wo1.x, x4, po);
        pi = fmaf(r.wi1.y, x5, pi); pg = fmaf(r.wg1.y, x5, pg); po = fmaf(r.wo1.y, x5, po);
        pi = fmaf(r.wi1.z, x6, pi); pg = fmaf(r.wg1.z, x6, pg); po = fmaf(r.wo1.z, x6, po);
        pi = fmaf(r.wi1.w, x7, pi); pg = fmaf(r.wg1.w, x7, pg); po = fmaf(r.wo1.w, x7, po);
        float c = fsig(pi) * ftanh(pg);
        float h = fsig(po) * ftanh(c);
        s[b] = cw * h;
    }
    // Batch-folding reduction over 64 lanes (Σ_h), 10 shuffles total.
    float u[4];
#pragma unroll
    for (int k = 0; k < 4; ++k) {
        float keep = (lane & 32) ? s[k + 4] : s[k];
        float send = (lane & 32) ? s[k]     : s[k + 4];
        u[k] = keep + __shfl_xor(send, 32, 64);
    }
    float v[2];
#pragma unroll
    for (int k = 0; k < 2; ++k) {
        float keep = (lane & 16) ? u[k + 2] : u[k];
        float send = (lane & 16) ? u[k]     : u[k + 2];
        v[k] = keep + __shfl_xor(send, 16, 64);
    }
    float keep = (lane & 8) ? v[1] : v[0];
    float send = (lane & 8) ? v[0] : v[1];
    float t = keep + __shfl_xor(send, 8, 64);
    t += __shfl_xor(t, 4, 64);
    t += __shfl_xor(t, 2, 64);
    t += __shfl_xor(t, 1, 64);
    if ((lane & 7) == 0) {
        int b = lane >> 3;
        atomicAdd(pout + b * MN + dst, ew * t);
    }
}

__global__ __launch_bounds__(256, 8) void edge_kernel(
        const float* __restrict__ xt,      // (MN, B, D)
        const float* __restrict__ edge_w,  // (E)
        const float* __restrict__ W,       // (E, 256, 8)
        const float* __restrict__ b_ih,    // (E, 256)
        const float* __restrict__ b_hh,    // (E, 256)
        const float* __restrict__ conv_w,  // (1, 64)
        const int*   __restrict__ src_idx,
        const int*   __restrict__ dst_idx,
        float* __restrict__ partial,       // (NCOPY, B, MN) zeroed by prep
        int E) {
    int lane = threadIdx.x & 63;
    int nw = gridDim.x * 4;
    int wid = blockIdx.x * 4 + (threadIdx.x >> 6);
    int e = __builtin_amdgcn_readfirstlane(wid);
    if (e >= E) return;
    float cw = conv_w[lane];
    float* pout = partial + (size_t)(wid & (NCOPY - 1)) * (BB * MN);

    int   srcC = src_idx[e], dstC = dst_idx[e];
    float ewC  = edge_w[e];

    while (true) {
        int eN = e + nw;
        bool hasN = (eN < E);
        // idx for next edge (s_load; hidden under this edge's load+compute).
        int srcN = 0, dstN = 0; float ewN = 0.0f;
        if (hasN) { srcN = src_idx[eN]; dstN = dst_idx[eN]; ewN = edge_w[eN]; }

        // Current edge burst + compute (8 waves/SIMD hide the wait).
        WRegs A;
        loadW(A, e, lane, W, b_ih, b_hh);
        float xA = xt[(size_t)srcC * 64 + lane];
        computeEdge(A, xA, dstC, ewC, cw, pout, lane);

        if (!hasN) break;
        e = eN; srcC = srcN; dstC = dstN; ewC = ewN;
    }
}

extern "C" void kernel_launch(void* const* d_in, const int* in_sizes, int n_in,
                              void* d_out, int out_size, void* d_ws, size_t ws_size,
                              hipStream_t stream) {
    const float* x      = (const float*)d_in[0];
    const float* edge_w = (const float*)d_in[1];
    const float* W_ih   = (const float*)d_in[2];
    const float* b_ih   = (const float*)d_in[3];
    const float* b_hh   = (const float*)d_in[4];
    const float* conv_w = (const float*)d_in[5];
    const float* conv_b = (const float*)d_in[6];
    const int* src_idx  = (const int*)d_in[7];
    const int* dst_idx  = (const int*)d_in[8];
    int E = in_sizes[1];

    float* xt      = (float*)d_ws;             // 65536 floats = 256 KB
    float* partial = (float*)d_ws + 65536;     // 32 x 8192 floats = 1 MB
    float* out     = (float*)d_out;            // 8192 floats

    prep_kernel<<<256, 256, 0, stream>>>(x, xt, partial);

    // 2048 blocks = 8/CU resident (launch_bounds(256,8)) = 32 waves/CU.
    edge_kernel<<<2048, 256, 0, stream>>>(xt, edge_w, W_ih, b_ih, b_hh,
                                          conv_w, src_idx, dst_idx, partial, E);

    reduce_kernel<<<32, 256, 0, stream>>>(partial, conv_b, out);
}